// Round 2
// baseline (411.391 us; speedup 1.0000x reference)
//
#include <hip/hip_runtime.h>
#include <hip/hip_fp16.h>
#include <math.h>

// SS2D fused block. B=2, H=W=64, L=4096, C=96, Di=192, K=4, N=16, R=6.
// Input dtype (bf16 vs f32) detected at runtime; internal compute f32/f16.
// Workspace: ~56 MB.

static constexpr int Bsz = 2;
static constexpr int Lc  = 4096;
static constexpr int Cc  = 96;
static constexpr int Dd  = 192;
static constexpr int Kk  = 4;
static constexpr int Nn  = 16;
static constexpr int NC  = 64;

__device__ __forceinline__ float bu(unsigned short v) {
    return __uint_as_float((unsigned int)v << 16);
}
__device__ __forceinline__ unsigned short f2b(float f) {
    unsigned int u = __float_as_uint(f);
    return (unsigned short)((u + 0x7fffu + ((u >> 16) & 1u)) >> 16);
}

// ---------------- K0: dtype detector (bf16 vs f32) ----------------
__global__ __launch_bounds__(256) void k0_detect(const unsigned short* __restrict__ x,
                                                 int* __restrict__ flag)
{
    __shared__ int s[256];
    int cnt = 0;
    for (int i = threadIdx.x; i < 4096; i += 256) {
        int e = (x[i] >> 7) & 0xFF;
        cnt += (e >= 118 && e <= 131) ? 1 : 0;
    }
    s[threadIdx.x] = cnt;
    __syncthreads();
    for (int st = 128; st > 0; st >>= 1) {
        if (threadIdx.x < st) s[threadIdx.x] += s[threadIdx.x + st];
        __syncthreads();
    }
    if (threadIdx.x == 0) flag[0] = (s[0] >= 3072) ? 1 : 0;
}

// ---------------- K0b: convert all inputs to canonical f32 ----------------
struct Cv {
    const void* src[12];
    int off[12];
    int n[12];
};
__global__ __launch_bounds__(256) void k0b_convert(Cv cv, const int* __restrict__ flag,
                                                   float* __restrict__ dstbase)
{
    int bf = flag[0];
    int t = blockIdx.y;
    int i = blockIdx.x * 256 + threadIdx.x;
    if (i >= cv.n[t]) return;
    float v;
    if (bf) v = bu(((const unsigned short*)cv.src[t])[i]);
    else    v = ((const float*)cv.src[t])[i];
    dstbase[cv.off[t] + i] = v;
}

// ---------------- K1: in_proj GEMM (8192x384x96), split xi / silu(z) ----------------
__global__ __launch_bounds__(256) void k1_inproj(const float* __restrict__ xf,
                                                 const float* __restrict__ wf,
                                                 float* __restrict__ xi, __half* __restrict__ zs)
{
    __shared__ float xT[32 * 97];
    __shared__ float wT[96 * 97];
    int tile = blockIdx.x >> 2, jq = blockIdx.x & 3;
    int b = tile >> 7;
    int l0 = (tile & 127) << 5;
    int j0 = jq * 96;
    for (int e = threadIdx.x; e < 32 * 96; e += 256) {
        int i = e / 96, c = e % 96;
        xT[i * 97 + c] = xf[(size_t)(b * Lc + l0 + i) * Cc + c];
    }
    for (int e = threadIdx.x; e < 96 * 96; e += 256) {
        int j = e / 96, c = e % 96;
        wT[j * 97 + c] = wf[(size_t)(j0 + j) * Cc + c];
    }
    __syncthreads();
    int jj = threadIdx.x & 31, ll = threadIdx.x >> 5;
    float acc[4][3];
#pragma unroll
    for (int i = 0; i < 4; i++)
#pragma unroll
        for (int m = 0; m < 3; m++) acc[i][m] = 0.f;
    for (int c = 0; c < 96; ++c) {
        float xv[4], wv[3];
#pragma unroll
        for (int i = 0; i < 4; i++) xv[i] = xT[(ll * 4 + i) * 97 + c];
#pragma unroll
        for (int m = 0; m < 3; m++) wv[m] = wT[(jj + 32 * m) * 97 + c];
#pragma unroll
        for (int i = 0; i < 4; i++)
#pragma unroll
            for (int m = 0; m < 3; m++) acc[i][m] += xv[i] * wv[m];
    }
#pragma unroll
    for (int i = 0; i < 4; i++) {
        int l = l0 + ll * 4 + i;
#pragma unroll
        for (int m = 0; m < 3; m++) {
            int j = j0 + jj + 32 * m;
            float v = acc[i][m];
            if (j < Dd) xi[(size_t)(b * Lc + l) * Dd + j] = v;
            else        zs[(size_t)(b * Lc + l) * Dd + (j - Dd)] = __float2half(v / (1.f + __expf(-v)));
        }
    }
}

// ---------------- K2: depthwise 3x3 conv + bias + SiLU, (B,L,Di)->(B,Di,L) ----------------
__global__ __launch_bounds__(192) void k2_conv(const float* __restrict__ xi,
                                               const float* __restrict__ cwf,
                                               const float* __restrict__ cbf,
                                               float* __restrict__ xc)
{
    __shared__ float ld[96 * 65];
    int bid = blockIdx.x;
    int dh = bid & 1, h = (bid >> 1) & 63, b = bid >> 7;
    int dl = threadIdx.x % 96, wset = threadIdx.x / 96;
    int d = dh * 96 + dl;
    float wgt[9];
#pragma unroll
    for (int t = 0; t < 9; t++) wgt[t] = cwf[d * 9 + t];
    float bias = cbf[d];
    for (int w = wset; w < 64; w += 2) {
        float acc = bias;
#pragma unroll
        for (int dy = -1; dy <= 1; ++dy) {
            int hh = h + dy;
            if (hh < 0 || hh >= 64) continue;
#pragma unroll
            for (int dx = -1; dx <= 1; ++dx) {
                int ww = w + dx;
                if (ww < 0 || ww >= 64) continue;
                acc += xi[(size_t)(b * Lc + hh * 64 + ww) * Dd + d] * wgt[(dy + 1) * 3 + (dx + 1)];
            }
        }
        ld[dl * 65 + w] = acc / (1.f + __expf(-acc));
    }
    __syncthreads();
    for (int e = threadIdx.x; e < 96 * 64; e += 192) {
        int d2 = e >> 6, w2 = e & 63;
        xc[((size_t)b * Dd + dh * 96 + d2) * Lc + h * 64 + w2] = ld[d2 * 65 + w2];
    }
}

// -------- K3: per-direction projection (38 outs) + dt-proj + softplus --------
// Directions 1,3 are processed in col-major sequence order: block covers seq
// positions s0..s0+63; the spatial position read from xc is transposed.
__global__ __launch_bounds__(256) void k3_proj(const float* __restrict__ xc,
                                               const float* __restrict__ xpwf,
                                               const float* __restrict__ dtwf,
                                               const float* __restrict__ dtbf,
                                               __half* __restrict__ dtH,
                                               __half* __restrict__ BsH, __half* __restrict__ CsH)
{
    __shared__ float Wl[192 * 40];
    __shared__ float dtWl[192 * 8];
    __shared__ float biasl[192];
    __shared__ float rawq[4][64 * 41];
    int bid = blockIdx.x;
    int pt = bid & 63, k = (bid >> 6) & 3, b = bid >> 8;
    bool colm = (k & 1);
    int s0 = pt * 64;
    for (int e = threadIdx.x; e < 38 * 192; e += 256) {
        int cp = e / 192, d = e % 192;
        Wl[d * 40 + cp] = xpwf[(size_t)(k * 38 + cp) * 192 + d];
    }
    for (int e = threadIdx.x; e < 2 * 192; e += 256) {
        Wl[(e >> 1) * 40 + 38 + (e & 1)] = 0.f;
    }
    for (int e = threadIdx.x; e < 192 * 6; e += 256) {
        int d = e / 6, r = e % 6;
        dtWl[d * 8 + r] = dtwf[(size_t)(k * 192 + d) * 6 + r];
    }
    for (int e = threadIdx.x; e < 192; e += 256) biasl[e] = dtbf[k * 192 + e];
    __syncthreads();
    int pi = threadIdx.x & 63, q = threadIdx.x >> 6;
    // spatial position for seq index s0+pi
    int pos = colm ? (pi * 64 + pt) : (pt * 64 + pi);
    float acc[40];
#pragma unroll
    for (int i = 0; i < 40; i++) acc[i] = 0.f;
    const float* xrow = xc + (size_t)b * Dd * Lc + pos;
    for (int dd = 0; dd < 48; ++dd) {
        int d = q * 48 + dd;
        float xv = xrow[(size_t)d * Lc];
#pragma unroll
        for (int c4 = 0; c4 < 10; ++c4) {
            float4 w4 = *reinterpret_cast<const float4*>(&Wl[d * 40 + c4 * 4]);
            acc[c4 * 4 + 0] += w4.x * xv; acc[c4 * 4 + 1] += w4.y * xv;
            acc[c4 * 4 + 2] += w4.z * xv; acc[c4 * 4 + 3] += w4.w * xv;
        }
    }
    float* myraw = &rawq[q][pi * 41];
#pragma unroll
    for (int i = 0; i < 40; i++) myraw[i] = acc[i];
    __syncthreads();
    for (int e = threadIdx.x; e < 64 * 40; e += 256) {
        int p = e / 40, cp = e % 40;
        rawq[0][p * 41 + cp] = rawq[0][p * 41 + cp] + rawq[1][p * 41 + cp]
                             + rawq[2][p * 41 + cp] + rawq[3][p * 41 + cp];
    }
    __syncthreads();
    for (int e = threadIdx.x; e < 64 * 16; e += 256) {
        int p = e >> 4, n = e & 15;
        size_t base = ((size_t)(b * Kk + k) * Lc + s0 + p) * 16 + n;
        BsH[base] = __float2half(rawq[0][p * 41 + 6 + n]);
        CsH[base] = __float2half(rawq[0][p * 41 + 22 + n]);
    }
    for (int dd = 0; dd < 48; ++dd) {
        int d = q * 48 + dd;
        float s = biasl[d];
#pragma unroll
        for (int r = 0; r < 6; r++) s += rawq[0][pi * 41 + r] * dtWl[d * 8 + r];
        float sp = fmaxf(s, 0.f) + log1pf(__expf(-fabsf(s)));
        dtH[((size_t)(b * Kk + k) * Dd + d) * Lc + s0 + pi] = __float2half(sp);
    }
}

// ---------------- K4: transpose u (xc) into col-major copy uT (f16) ----------------
__global__ __launch_bounds__(256) void k4_ut(const float* __restrict__ xc,
                                             __half* __restrict__ uT)
{
    __shared__ float t[64 * 65];
    int bid = blockIdx.x;
    int d = bid % Dd, b = bid / Dd;
    const float* src = xc + ((size_t)b * Dd + d) * Lc;
    __half* dst = uT + ((size_t)b * Dd + d) * Lc;
    for (int e = threadIdx.x; e < 4096; e += 256)
        t[(e >> 6) * 65 + (e & 63)] = src[e];
    __syncthreads();
    for (int e = threadIdx.x; e < 4096; e += 256)
        dst[e] = __float2half(t[(e & 63) * 65 + (e >> 6)]);
}

// ---------------- K5: scan pass 1 (per-chunk prodA, local state) ----------------
__global__ __launch_bounds__(256) void k5_pass1(const __half* __restrict__ dtH,
                                                const float* __restrict__ xc, const __half* __restrict__ uT,
                                                const __half* __restrict__ BsH,
                                                const float* __restrict__ alogf,
                                                float* __restrict__ P, float* __restrict__ S)
{
    int bid = blockIdx.x;
    int c = bid & 63;
    int t1 = bid >> 6;
    int dg = t1 % 12, k = (t1 / 12) & 3, b = t1 / 48;
    int n = threadIdx.x & 15, dl = threadIdx.x >> 4;
    int d = dg * 16 + dl;
    bool colm = (k & 1);
    const __half* dtp = dtH + ((size_t)(b * Kk + k) * Dd + d) * Lc;
    const float* upf = xc + ((size_t)b * Dd + d) * Lc;
    const __half* uph = uT + ((size_t)b * Dd + d) * Lc;
    const __half* Bp = BsH + (size_t)(b * Kk + k) * Lc * 16;
    bool rev = (k >= 2);
    float An = -__expf(alogf[(size_t)(k * Dd + d) * 16 + n]);
    float Pp = 1.f, h = 0.f;
    int t0 = c * 64;
    for (int i = 0; i < 64; ++i) {
        int t = t0 + i;
        int ai = rev ? (Lc - 1 - t) : t;
        float dtv = __half2float(dtp[ai]);
        float uv = colm ? __half2float(uph[ai]) : upf[ai];
        float bv = __half2float(Bp[(size_t)ai * 16 + n]);
        float a = __expf(dtv * An);
        h = a * h + dtv * uv * bv;
        Pp *= a;
    }
    size_t idx = (((size_t)(b * Kk + k) * Dd + d) * NC + c) * 16 + n;
    P[idx] = Pp; S[idx] = h;
}

// ---------------- K6: chunk-level scan; Hin written in place over P ----------------
__global__ __launch_bounds__(256) void k6_pass2(float* __restrict__ P, const float* __restrict__ S)
{
    int g = blockIdx.x * 256 + threadIdx.x;   // 24576 chains*n
    int n = g & 15;
    int chain = g >> 4;
    size_t base = (size_t)chain * NC * 16 + n;
    float h = 0.f;
    for (int c = 0; c < NC; ++c) {
        size_t id = base + (size_t)c * 16;
        float p = P[id], s = S[id];
        P[id] = h;                 // exclusive carry-in for chunk c
        h = p * h + s;
    }
}

// ---------------- K7: scan pass 3 (recompute with true state, emit y f16) ----------------
__global__ __launch_bounds__(256) void k7_pass3(const __half* __restrict__ dtH,
                                                const float* __restrict__ xc, const __half* __restrict__ uT,
                                                const __half* __restrict__ BsH, const __half* __restrict__ CsH,
                                                const float* __restrict__ alogf,
                                                const float* __restrict__ dsf,
                                                const float* __restrict__ Hin,
                                                __half* __restrict__ ysH)
{
    int bid = blockIdx.x;
    int c = bid & 63;
    int t1 = bid >> 6;
    int dg = t1 % 12, k = (t1 / 12) & 3, b = t1 / 48;
    int n = threadIdx.x & 15, dl = threadIdx.x >> 4;
    int d = dg * 16 + dl;
    bool colm = (k & 1);
    const __half* dtp = dtH + ((size_t)(b * Kk + k) * Dd + d) * Lc;
    const float* upf = xc + ((size_t)b * Dd + d) * Lc;
    const __half* uph = uT + ((size_t)b * Dd + d) * Lc;
    const __half* Bp = BsH + (size_t)(b * Kk + k) * Lc * 16;
    const __half* Cp = CsH + (size_t)(b * Kk + k) * Lc * 16;
    bool rev = (k >= 2);
    float An = -__expf(alogf[(size_t)(k * Dd + d) * 16 + n]);
    float Dsv = dsf[k * Dd + d];
    float h = Hin[(((size_t)(b * Kk + k) * Dd + d) * NC + c) * 16 + n];
    __half* yrow = ysH + ((size_t)(k * Bsz + b) * Dd + d) * Lc;
    int t0 = c * 64;
    float ystash = 0.f;
    for (int i = 0; i < 64; ++i) {
        int t = t0 + i;
        int ai = rev ? (Lc - 1 - t) : t;
        float dtv = __half2float(dtp[ai]);
        float uv = colm ? __half2float(uph[ai]) : upf[ai];
        float bv = __half2float(Bp[(size_t)ai * 16 + n]);
        float cv = __half2float(Cp[(size_t)ai * 16 + n]);
        float a = __expf(dtv * An);
        h = a * h + dtv * uv * bv;
        float yv = h * cv;
        yv += __shfl_xor(yv, 1, 16);
        yv += __shfl_xor(yv, 2, 16);
        yv += __shfl_xor(yv, 4, 16);
        yv += __shfl_xor(yv, 8, 16);
        if ((i & 15) == n) ystash = yv + uv * Dsv;
        if ((i & 15) == 15) {
            int tb = t0 + (i & ~15) + n;
            int aib = rev ? (Lc - 1 - tb) : tb;
            yrow[aib] = __float2half(ystash);
        }
    }
}

// ------- K9: merge 4 dirs + LayerNorm + SiLU(z) gate + out_proj + store -------
__global__ __launch_bounds__(256) void k9_final(const __half* __restrict__ ysH,
                                                const __half* __restrict__ zsH,
                                                const float* __restrict__ nwf, const float* __restrict__ nbf,
                                                const float* __restrict__ wof,
                                                const int* __restrict__ flag,
                                                void* __restrict__ outv)
{
    __shared__ float yt[192 * 64];
    __shared__ float ps1[256], ps2[256];
    __shared__ float mu[64], rs[64];
    int bf = flag[0];
    int bid = blockIdx.x;
    int pt = bid & 63, b = bid >> 6;
    int p0 = pt * 64;
    for (int e = threadIdx.x; e < 192 * 64; e += 256) {
        int d = e >> 6, w = e & 63;
        int p = p0 + w;
        int qq = w * 64 + pt;   // col-major index of same spatial position
        size_t r0 = ((size_t)(0 * Bsz + b) * Dd + d) * Lc;
        size_t r1 = ((size_t)(1 * Bsz + b) * Dd + d) * Lc;
        size_t r2 = ((size_t)(2 * Bsz + b) * Dd + d) * Lc;
        size_t r3 = ((size_t)(3 * Bsz + b) * Dd + d) * Lc;
        yt[e] = __half2float(ysH[r0 + p]) + __half2float(ysH[r2 + p])
              + __half2float(ysH[r1 + qq]) + __half2float(ysH[r3 + qq]);
    }
    __syncthreads();
    {
        int w = threadIdx.x & 63, q = threadIdx.x >> 6;
        float s1 = 0.f, s2 = 0.f;
        for (int dd = 0; dd < 48; ++dd) {
            float v = yt[(q * 48 + dd) * 64 + w];
            s1 += v; s2 += v * v;
        }
        ps1[q * 64 + w] = s1; ps2[q * 64 + w] = s2;
    }
    __syncthreads();
    if (threadIdx.x < 64) {
        int w = threadIdx.x;
        float s1 = ps1[w] + ps1[64 + w] + ps1[128 + w] + ps1[192 + w];
        float s2 = ps2[w] + ps2[64 + w] + ps2[128 + w] + ps2[192 + w];
        float m = s1 * (1.f / 192.f);
        float var = s2 * (1.f / 192.f) - m * m;
        mu[w] = m; rs[w] = rsqrtf(var + 1e-5f);
    }
    __syncthreads();
    for (int e = threadIdx.x; e < 192 * 64; e += 256) {
        int d = e >> 6, w = e & 63;
        float v = (yt[e] - mu[w]) * rs[w];
        v = v * nwf[d] + nbf[d];
        float zv = __half2float(zsH[((size_t)b * Lc + p0 + w) * Dd + d]);
        yt[e] = v * zv;
    }
    __syncthreads();
    int w = threadIdx.x & 63, cg = threadIdx.x >> 6;
    float acc[24];
#pragma unroll
    for (int i = 0; i < 24; i++) acc[i] = 0.f;
    for (int d0 = 0; d0 < 192; d0 += 32) {
        float g[32];
#pragma unroll
        for (int i = 0; i < 32; i++) g[i] = yt[(d0 + i) * 64 + w];
#pragma unroll
        for (int cc = 0; cc < 24; ++cc) {
            const float* wrow = wof + (size_t)(cg * 24 + cc) * 192 + d0;
#pragma unroll
            for (int i4 = 0; i4 < 8; i4++) {
                float4 w4 = *reinterpret_cast<const float4*>(wrow + i4 * 4);
                acc[cc] += g[i4 * 4 + 0] * w4.x + g[i4 * 4 + 1] * w4.y
                         + g[i4 * 4 + 2] * w4.z + g[i4 * 4 + 3] * w4.w;
            }
        }
    }
    size_t obase = ((size_t)b * Lc + p0 + w) * Cc + cg * 24;
    if (bf) {
        unsigned short* o = (unsigned short*)outv;
#pragma unroll
        for (int cc = 0; cc < 24; ++cc) o[obase + cc] = f2b(acc[cc]);
    } else {
        float* o = (float*)outv;
#pragma unroll
        for (int cc = 0; cc < 24; ++cc) o[obase + cc] = acc[cc];
    }
}

extern "C" void kernel_launch(void* const* d_in, const int* in_sizes, int n_in,
                              void* d_out, int out_size, void* d_ws, size_t ws_size,
                              hipStream_t stream)
{
    (void)out_size; (void)ws_size;
    float* ws = (float*)d_ws;
    int* flag = (int*)ws;                       // @0 (64-float slot)

    // converted-input region
    const int base_cvt = 64;
    int off[12], tot = 0;
    for (int i = 0; i < 12; ++i) {
        off[i] = base_cvt + tot;
        int n = (i < n_in) ? in_sizes[i] : 0;
        tot += (n + 63) & ~63;
    }
    float* xf   = ws + off[0];
    float* winf = ws + off[1];
    float* cwf  = ws + off[2];
    float* cbf  = ws + off[3];
    float* xpwf = ws + off[4];
    float* dtwf = ws + off[5];
    float* dtbf = ws + off[6];
    float* alogf= ws + off[7];
    float* dsf  = ws + off[8];
    float* nwf  = ws + off[9];
    float* nbf  = ws + off[10];
    float* wof  = ws + off[11];
    int o = base_cvt + tot;                     // ≈ 891712

    __half* dtH = (__half*)(ws + o);  o += 3145728;   // (B,K,Di,L) f16, per-k seq order
    float*  xc  = ws + o;             o += 1572864;   // (B,Di,L) f32
    __half* uT  = (__half*)(ws + o);  o += 786432;    // (B,Di,L) f16, col-major
    __half* BsH = (__half*)(ws + o);  o += 262144;    // (B,K,L,N) f16, per-k seq order
    __half* CsH = (__half*)(ws + o);  o += 262144;
    float*  P   = ws + o;             o += 1572864;   // (B,K,Di,NC,N); becomes Hin in k6
    float*  S   = ws + o;             o += 1572864;
    __half* zsH = (__half*)(ws + o);  o += 786432;    // (B,L,Di) f16
    float*  xi  = ws + o;                              // alias: xi (f32, 1572864) ...
    __half* ysH = (__half*)(ws + o);  o += 3145728;   // ... then ys (K,B,Di,L) f16
    // total ≈ 14.0M floats ≈ 56 MB

    Cv cv;
    for (int i = 0; i < 12; ++i) {
        cv.src[i] = (i < n_in) ? d_in[i] : d_in[0];
        cv.off[i] = off[i];
        cv.n[i]   = (i < n_in) ? in_sizes[i] : 0;
    }

    k0_detect  <<<dim3(1),    dim3(256), 0, stream>>>((const unsigned short*)d_in[0], flag);
    k0b_convert<<<dim3(3072, 12), dim3(256), 0, stream>>>(cv, flag, ws);
    k1_inproj  <<<dim3(1024), dim3(256), 0, stream>>>(xf, winf, xi, zsH);
    k2_conv    <<<dim3(256),  dim3(192), 0, stream>>>(xi, cwf, cbf, xc);
    k3_proj    <<<dim3(512),  dim3(256), 0, stream>>>(xc, xpwf, dtwf, dtbf, dtH, BsH, CsH);
    k4_ut      <<<dim3(384),  dim3(256), 0, stream>>>(xc, uT);
    k5_pass1   <<<dim3(6144), dim3(256), 0, stream>>>(dtH, xc, uT, BsH, alogf, P, S);
    k6_pass2   <<<dim3(96),   dim3(256), 0, stream>>>(P, S);
    k7_pass3   <<<dim3(6144), dim3(256), 0, stream>>>(dtH, xc, uT, BsH, CsH, alogf, dsf, P, ysH);
    k9_final   <<<dim3(128),  dim3(256), 0, stream>>>(ysH, zsH, nwf, nbf, wof, flag, d_out);
}

// Round 3
// 365.537 us; speedup vs baseline: 1.1254x; 1.1254x over previous
//
#include <hip/hip_runtime.h>
#include <hip/hip_fp16.h>
#include <math.h>

// SS2D fused block. B=2, H=W=64, L=4096, C=96, Di=192, K=4, N=16, R=6.
// Input dtype (bf16 vs f32) detected at runtime; internal compute f32 (dt/z/ys f16).
// Workspace: ~52 MB.

static constexpr int Bsz = 2;
static constexpr int Lc  = 4096;
static constexpr int Cc  = 96;
static constexpr int Dd  = 192;
static constexpr int Kk  = 4;
static constexpr int NC  = 32;     // chunks of 128 steps

__device__ __forceinline__ float bu(unsigned short v) {
    return __uint_as_float((unsigned int)v << 16);
}
__device__ __forceinline__ unsigned short f2b(float f) {
    unsigned int u = __float_as_uint(f);
    return (unsigned short)((u + 0x7fffu + ((u >> 16) & 1u)) >> 16);
}

// ---------------- K0: dtype detector (bf16 vs f32) ----------------
__global__ __launch_bounds__(256) void k0_detect(const unsigned short* __restrict__ x,
                                                 int* __restrict__ flag)
{
    __shared__ int s[256];
    int cnt = 0;
    for (int i = threadIdx.x; i < 4096; i += 256) {
        int e = (x[i] >> 7) & 0xFF;
        cnt += (e >= 118 && e <= 131) ? 1 : 0;
    }
    s[threadIdx.x] = cnt;
    __syncthreads();
    for (int st = 128; st > 0; st >>= 1) {
        if (threadIdx.x < st) s[threadIdx.x] += s[threadIdx.x + st];
        __syncthreads();
    }
    if (threadIdx.x == 0) flag[0] = (s[0] >= 3072) ? 1 : 0;
}

// ---------------- K0b: convert weight inputs (1..11) to canonical f32 ----------------
struct Cv {
    const void* src[11];
    int off[11];
    int n[11];
};
__global__ __launch_bounds__(256) void k0b_convert(Cv cv, const int* __restrict__ flag,
                                                   float* __restrict__ dstbase)
{
    int bf = flag[0];
    int t = blockIdx.y;
    int i = blockIdx.x * 256 + threadIdx.x;
    if (i >= cv.n[t]) return;
    float v;
    if (bf) v = bu(((const unsigned short*)cv.src[t])[i]);
    else    v = ((const float*)cv.src[t])[i];
    dstbase[cv.off[t] + i] = v;
}

// ---------------- K1: in_proj GEMM (8192x384x96), split xi / silu(z) ----------------
__global__ __launch_bounds__(256) void k1_inproj(const void* __restrict__ xraw,
                                                 const int* __restrict__ flag,
                                                 const float* __restrict__ wf,
                                                 float* __restrict__ xi, __half* __restrict__ zs)
{
    __shared__ float xT[32 * 97];
    __shared__ float wT[96 * 97];
    const int bf = flag[0];
    int tile = blockIdx.x >> 2, jq = blockIdx.x & 3;
    int b = tile >> 7;
    int l0 = (tile & 127) << 5;
    int j0 = jq * 96;
    for (int e = threadIdx.x; e < 32 * 96; e += 256) {
        int i = e / 96, c = e % 96;
        size_t idx = (size_t)(b * Lc + l0 + i) * Cc + c;
        xT[i * 97 + c] = bf ? bu(((const unsigned short*)xraw)[idx])
                            : ((const float*)xraw)[idx];
    }
    for (int e = threadIdx.x; e < 96 * 96; e += 256) {
        int j = e / 96, c = e % 96;
        wT[j * 97 + c] = wf[(size_t)(j0 + j) * Cc + c];
    }
    __syncthreads();
    int jj = threadIdx.x & 31, ll = threadIdx.x >> 5;
    float acc[4][3];
#pragma unroll
    for (int i = 0; i < 4; i++)
#pragma unroll
        for (int m = 0; m < 3; m++) acc[i][m] = 0.f;
    for (int c = 0; c < 96; ++c) {
        float xv[4], wv[3];
#pragma unroll
        for (int i = 0; i < 4; i++) xv[i] = xT[(ll * 4 + i) * 97 + c];
#pragma unroll
        for (int m = 0; m < 3; m++) wv[m] = wT[(jj + 32 * m) * 97 + c];
#pragma unroll
        for (int i = 0; i < 4; i++)
#pragma unroll
            for (int m = 0; m < 3; m++) acc[i][m] += xv[i] * wv[m];
    }
#pragma unroll
    for (int i = 0; i < 4; i++) {
        int l = l0 + ll * 4 + i;
#pragma unroll
        for (int m = 0; m < 3; m++) {
            int j = j0 + jj + 32 * m;
            float v = acc[i][m];
            if (j < Dd) xi[(size_t)(b * Lc + l) * Dd + j] = v;
            else        zs[(size_t)(b * Lc + l) * Dd + (j - Dd)] = __float2half(v / (1.f + __expf(-v)));
        }
    }
}

// ---------------- K2: depthwise 3x3 conv + bias + SiLU, (B,L,Di)->(B,Di,L) ----------------
__global__ __launch_bounds__(192) void k2_conv(const float* __restrict__ xi,
                                               const float* __restrict__ cwf,
                                               const float* __restrict__ cbf,
                                               float* __restrict__ xc)
{
    __shared__ float ld[96 * 65];
    int bid = blockIdx.x;
    int dh = bid & 1, h = (bid >> 1) & 63, b = bid >> 7;
    int dl = threadIdx.x % 96, wset = threadIdx.x / 96;
    int d = dh * 96 + dl;
    float wgt[9];
#pragma unroll
    for (int t = 0; t < 9; t++) wgt[t] = cwf[d * 9 + t];
    float bias = cbf[d];
    for (int w = wset; w < 64; w += 2) {
        float acc = bias;
#pragma unroll
        for (int dy = -1; dy <= 1; ++dy) {
            int hh = h + dy;
            if (hh < 0 || hh >= 64) continue;
#pragma unroll
            for (int dx = -1; dx <= 1; ++dx) {
                int ww = w + dx;
                if (ww < 0 || ww >= 64) continue;
                acc += xi[(size_t)(b * Lc + hh * 64 + ww) * Dd + d] * wgt[(dy + 1) * 3 + (dx + 1)];
            }
        }
        ld[dl * 65 + w] = acc / (1.f + __expf(-acc));
    }
    __syncthreads();
    for (int e = threadIdx.x; e < 96 * 64; e += 192) {
        int d2 = e >> 6, w2 = e & 63;
        xc[((size_t)b * Dd + dh * 96 + d2) * Lc + h * 64 + w2] = ld[d2 * 65 + w2];
    }
}

// -------- K3: per-direction projection (38 outs) + dt-proj + softplus --------
// All outputs stored in SPATIAL order (row-spatial for k even, col-spatial for k odd);
// reversed directions are handled by the scan's REV traversal.
__global__ __launch_bounds__(256) void k3_proj(const float* __restrict__ xc,
                                               const float* __restrict__ xpwf,
                                               const float* __restrict__ dtwf,
                                               const float* __restrict__ dtbf,
                                               __half* __restrict__ dtH,
                                               float* __restrict__ BsT, float* __restrict__ CsT)
{
    __shared__ float Wl[192 * 40];
    __shared__ float dtWl[192 * 8];
    __shared__ float biasl[192];
    __shared__ float rawq[4][64 * 41];
    int bid = blockIdx.x;
    int pt = bid & 63, k = (bid >> 6) & 3, b = bid >> 8;
    bool colm = (k & 1);
    int s0 = pt * 64;
    for (int e = threadIdx.x; e < 38 * 192; e += 256) {
        int cp = e / 192, d = e % 192;
        Wl[d * 40 + cp] = xpwf[(size_t)(k * 38 + cp) * 192 + d];
    }
    for (int e = threadIdx.x; e < 2 * 192; e += 256) {
        Wl[(e >> 1) * 40 + 38 + (e & 1)] = 0.f;
    }
    for (int e = threadIdx.x; e < 192 * 6; e += 256) {
        int d = e / 6, r = e % 6;
        dtWl[d * 8 + r] = dtwf[(size_t)(k * 192 + d) * 6 + r];
    }
    for (int e = threadIdx.x; e < 192; e += 256) biasl[e] = dtbf[k * 192 + e];
    __syncthreads();
    int pi = threadIdx.x & 63, q = threadIdx.x >> 6;
    int pos = colm ? (pi * 64 + pt) : (pt * 64 + pi);
    float acc[40];
#pragma unroll
    for (int i = 0; i < 40; i++) acc[i] = 0.f;
    const float* xrow = xc + (size_t)b * Dd * Lc + pos;
    for (int dd = 0; dd < 48; ++dd) {
        int d = q * 48 + dd;
        float xv = xrow[(size_t)d * Lc];
#pragma unroll
        for (int c4 = 0; c4 < 10; ++c4) {
            float4 w4 = *reinterpret_cast<const float4*>(&Wl[d * 40 + c4 * 4]);
            acc[c4 * 4 + 0] += w4.x * xv; acc[c4 * 4 + 1] += w4.y * xv;
            acc[c4 * 4 + 2] += w4.z * xv; acc[c4 * 4 + 3] += w4.w * xv;
        }
    }
    float* myraw = &rawq[q][pi * 41];
#pragma unroll
    for (int i = 0; i < 40; i++) myraw[i] = acc[i];
    __syncthreads();
    for (int e = threadIdx.x; e < 64 * 40; e += 256) {
        int p = e / 40, cp = e % 40;
        rawq[0][p * 41 + cp] = rawq[0][p * 41 + cp] + rawq[1][p * 41 + cp]
                             + rawq[2][p * 41 + cp] + rawq[3][p * 41 + cp];
    }
    __syncthreads();
    // B/C transposed: [ (b,k) ][ n ][ t ]  (f32)
    for (int e = threadIdx.x; e < 64 * 16; e += 256) {
        int n = e >> 6, p = e & 63;
        size_t base = ((size_t)((b * Kk + k) * 16 + n)) * Lc + s0 + p;
        BsT[base] = rawq[0][p * 41 + 6 + n];
        CsT[base] = rawq[0][p * 41 + 22 + n];
    }
    for (int dd = 0; dd < 48; ++dd) {
        int d = q * 48 + dd;
        float s = biasl[d];
#pragma unroll
        for (int r = 0; r < 6; r++) s += rawq[0][pi * 41 + r] * dtWl[d * 8 + r];
        float sp = fmaxf(s, 0.f) + log1pf(__expf(-fabsf(s)));
        dtH[((size_t)(b * Kk + k) * Dd + d) * Lc + s0 + pi] = __float2half(sp);
    }
}

// ---------------- K4: transpose xc into col-major copy uT (f32) ----------------
__global__ __launch_bounds__(256) void k4_ut(const float* __restrict__ xc,
                                             float* __restrict__ uT)
{
    __shared__ float t[64 * 65];
    int bid = blockIdx.x;
    int d = bid % Dd, b = bid / Dd;
    const float* src = xc + ((size_t)b * Dd + d) * Lc;
    float* dst = uT + ((size_t)b * Dd + d) * Lc;
    for (int e = threadIdx.x; e < 4096; e += 256)
        t[(e >> 6) * 65 + (e & 63)] = src[e];
    __syncthreads();
    for (int e = threadIdx.x; e < 4096; e += 256)
        dst[e] = t[(e & 63) * 65 + (e >> 6)];
}

// ---------------- KSCAN: chunked selective scan (pass1 / pass3) ----------------
// grid: NC x (12 dg x 2 k-sub x 2 b) = 1536 blocks per (REV) launch, 256 thr.
template<int REV, int PASS3>
__global__ __launch_bounds__(256) void kscan(const __half* __restrict__ dtH,
                                             const float* __restrict__ xc,
                                             const float* __restrict__ uT,
                                             const float* __restrict__ BsT,
                                             const float* __restrict__ CsT,
                                             const float* __restrict__ alogf,
                                             const float* __restrict__ dsf,
                                             float* __restrict__ P,       // pass1: out; pass3: Hin
                                             float* __restrict__ S,       // pass1 out
                                             __half* __restrict__ ysH,
                                             int kbase)
{
    int c  = blockIdx.x & 31;
    int t1 = blockIdx.x >> 5;
    int dg = t1 % 12;
    int kk = kbase + ((t1 / 12) & 1);
    int b  = t1 / 24;
    int n  = threadIdx.x & 15, dl = threadIdx.x >> 4;
    int d  = dg * 16 + dl;

    const __half* dtp = dtH + ((size_t)((b * Kk + kk) * Dd + d)) * Lc;
    const float*  up  = (kk & 1) ? uT + (size_t)(b * Dd + d) * Lc
                                 : xc + (size_t)(b * Dd + d) * Lc;
    const float*  Bn  = BsT + ((size_t)((b * Kk + kk) * 16 + n)) * Lc;
    const float*  Cn  = CsT + ((size_t)((b * Kk + kk) * 16 + n)) * Lc;
    float An = -__expf(alogf[(kk * Dd + d) * 16 + n]);
    size_t pidx = (((size_t)(b * Kk + kk) * Dd + d) * NC + c) * 16 + n;

    float h, sdt = 0.f, Dsv = 0.f, ystash = 0.f;
    __half* yrow = nullptr;
    if (PASS3) {
        h = P[pidx];                       // carry-in
        Dsv = dsf[kk * Dd + d];
        yrow = ysH + ((size_t)(kk * Bsz + b) * Dd + d) * Lc;
    } else h = 0.f;

    int t0 = c * 128;
    for (int s = 0; s < 8; ++s) {
        int tg = t0 + s * 16;
        int mb = REV ? (Lc - 16 - tg) : tg;     // aligned 16-element base
        float4 uq[4], bq[4], cq[4];
        {
            const float4* p4 = reinterpret_cast<const float4*>(up + mb);
            uq[0] = p4[0]; uq[1] = p4[1]; uq[2] = p4[2]; uq[3] = p4[3];
        }
        {
            const float4* p4 = reinterpret_cast<const float4*>(Bn + mb);
            bq[0] = p4[0]; bq[1] = p4[1]; bq[2] = p4[2]; bq[3] = p4[3];
        }
        if (PASS3) {
            const float4* p4 = reinterpret_cast<const float4*>(Cn + mb);
            cq[0] = p4[0]; cq[1] = p4[1]; cq[2] = p4[2]; cq[3] = p4[3];
        }
        __half2 dh[8];
        {
            const __half2* p2 = reinterpret_cast<const __half2*>(dtp + mb);
#pragma unroll
            for (int i = 0; i < 8; ++i) dh[i] = p2[i];
        }
#pragma unroll
        for (int j = 0; j < 16; ++j) {
            const int m = REV ? (15 - j) : j;
            float dtv = (m & 1) ? __high2float(dh[m >> 1]) : __low2float(dh[m >> 1]);
            float uv  = reinterpret_cast<const float*>(uq)[m];
            float bv  = reinterpret_cast<const float*>(bq)[m];
            float a   = __expf(dtv * An);
            if (!PASS3) sdt += dtv;
            h = a * h + (dtv * uv) * bv;
            if (PASS3) {
                float cv = reinterpret_cast<const float*>(cq)[m];
                float yv = h * cv;
                yv += __shfl_xor(yv, 1, 16);
                yv += __shfl_xor(yv, 2, 16);
                yv += __shfl_xor(yv, 4, 16);
                yv += __shfl_xor(yv, 8, 16);
                if (j == n) ystash = yv + uv * Dsv;
            }
        }
        if (PASS3) {
            int tb = tg + n;
            int aw = REV ? (Lc - 1 - tb) : tb;
            yrow[aw] = __float2half(ystash);    // 16-lane coalesced
        }
    }
    if (!PASS3) {
        P[pidx] = __expf(An * sdt);             // prod of a over chunk
        S[pidx] = h;
    }
}

// ---------------- K6: chunk-level scan; carry-in written in place over P ----------------
__global__ __launch_bounds__(256) void k6_pass2(float* __restrict__ P, const float* __restrict__ S)
{
    int g = blockIdx.x * 256 + threadIdx.x;   // 24576
    int n = g & 15;
    int chain = g >> 4;
    size_t base = (size_t)chain * NC * 16 + n;
    float h = 0.f;
    for (int c = 0; c < NC; ++c) {
        size_t id = base + (size_t)c * 16;
        float p = P[id], s = S[id];
        P[id] = h;
        h = p * h + s;
    }
}

// ---------------- K8t: ysT = transpose(ys1 + ys3) per (b,d) ----------------
__global__ __launch_bounds__(256) void k8t(const __half* __restrict__ ysH,
                                           __half* __restrict__ ysT)
{
    __shared__ float t[64 * 65];
    int bid = blockIdx.x;
    int d = bid % Dd, b = bid / Dd;
    const __half* y1 = ysH + ((size_t)(1 * Bsz + b) * Dd + d) * Lc;
    const __half* y3 = ysH + ((size_t)(3 * Bsz + b) * Dd + d) * Lc;
    __half* dst = ysT + ((size_t)b * Dd + d) * Lc;
    for (int e = threadIdx.x; e < 4096; e += 256)
        t[(e >> 6) * 65 + (e & 63)] = __half2float(y1[e]) + __half2float(y3[e]);
    __syncthreads();
    for (int e = threadIdx.x; e < 4096; e += 256)
        dst[e] = __float2half(t[(e & 63) * 65 + (e >> 6)]);
}

// ---------------- K8: merge + LayerNorm + SiLU(z) gate -> gH ----------------
__global__ __launch_bounds__(256) void k8_norm(const __half* __restrict__ ysH,
                                               const __half* __restrict__ ysT,
                                               const __half* __restrict__ zsH,
                                               const float* __restrict__ nwf,
                                               const float* __restrict__ nbf,
                                               __half* __restrict__ gH)
{
    __shared__ float yt[192 * 33];
    __shared__ float ps1[8 * 32], ps2[8 * 32];
    __shared__ float mu[32], rs[32];
    int bid = blockIdx.x;
    int pt = bid & 127, b = bid >> 7;
    int p0 = pt * 32;
    for (int e = threadIdx.x; e < 192 * 32; e += 256) {
        int d = e >> 5, p = e & 31;
        size_t r0 = ((size_t)(0 * Bsz + b) * Dd + d) * Lc + p0 + p;
        size_t r2 = ((size_t)(2 * Bsz + b) * Dd + d) * Lc + p0 + p;
        size_t rt = ((size_t)b * Dd + d) * Lc + p0 + p;
        yt[d * 33 + p] = __half2float(ysH[r0]) + __half2float(ysH[r2]) + __half2float(ysT[rt]);
    }
    __syncthreads();
    {
        int p = threadIdx.x & 31, q = threadIdx.x >> 5;
        float s1 = 0.f, s2 = 0.f;
        for (int dd = 0; dd < 24; ++dd) {
            float v = yt[(q * 24 + dd) * 33 + p];
            s1 += v; s2 += v * v;
        }
        ps1[q * 32 + p] = s1; ps2[q * 32 + p] = s2;
    }
    __syncthreads();
    if (threadIdx.x < 32) {
        int p = threadIdx.x;
        float s1 = 0.f, s2 = 0.f;
        for (int q = 0; q < 8; ++q) { s1 += ps1[q * 32 + p]; s2 += ps2[q * 32 + p]; }
        float m = s1 * (1.f / 192.f);
        float var = s2 * (1.f / 192.f) - m * m;
        mu[p] = m; rs[p] = rsqrtf(var + 1e-5f);
    }
    __syncthreads();
    for (int i = threadIdx.x; i < 32 * 192; i += 256) {
        int p = i / 192, d = i - p * 192;
        float v = (yt[d * 33 + p] - mu[p]) * rs[p] * nwf[d] + nbf[d];
        size_t addr = ((size_t)b * Lc + p0 + p) * Dd + d;
        float zv = __half2float(zsH[addr]);
        gH[addr] = __float2half(v * zv);
    }
}

// ---------------- K10: out_proj GEMM (8192 x 96 x 192) ----------------
__global__ __launch_bounds__(256) void k10_outproj(const __half* __restrict__ gH,
                                                   const float* __restrict__ wof,
                                                   const int* __restrict__ flag,
                                                   void* __restrict__ outv)
{
    __shared__ float wT[192 * 100];   // [d][c], padded
    const int bf = flag[0];
    for (int e = threadIdx.x; e < 96 * 192; e += 256) {
        int cI = e / 192, dI = e - cI * 192;
        wT[dI * 100 + cI] = wof[e];
    }
    __syncthreads();
    int r0 = blockIdx.x * 32;
    int r = threadIdx.x >> 3, cg = threadIdx.x & 7;
    const __half* grow = gH + (size_t)(r0 + r) * Dd;
    float acc[12];
#pragma unroll
    for (int i = 0; i < 12; ++i) acc[i] = 0.f;
    for (int d0 = 0; d0 < 192; d0 += 8) {
        __half2 g2[4];
        *reinterpret_cast<uint4*>(g2) = *reinterpret_cast<const uint4*>(grow + d0);
#pragma unroll
        for (int j = 0; j < 8; ++j) {
            float gf = (j & 1) ? __high2float(g2[j >> 1]) : __low2float(g2[j >> 1]);
            const float* wrow = &wT[(d0 + j) * 100 + cg * 12];
            float4 w0 = *reinterpret_cast<const float4*>(wrow);
            float4 w1 = *reinterpret_cast<const float4*>(wrow + 4);
            float4 w2 = *reinterpret_cast<const float4*>(wrow + 8);
            acc[0] += gf * w0.x; acc[1] += gf * w0.y; acc[2]  += gf * w0.z; acc[3]  += gf * w0.w;
            acc[4] += gf * w1.x; acc[5] += gf * w1.y; acc[6]  += gf * w1.z; acc[7]  += gf * w1.w;
            acc[8] += gf * w2.x; acc[9] += gf * w2.y; acc[10] += gf * w2.z; acc[11] += gf * w2.w;
        }
    }
    size_t obase = (size_t)(r0 + r) * Cc + cg * 12;
    if (bf) {
        unsigned short* o = (unsigned short*)outv;
#pragma unroll
        for (int cc = 0; cc < 12; ++cc) o[obase + cc] = f2b(acc[cc]);
    } else {
        float* o = (float*)outv;
#pragma unroll
        for (int cc = 0; cc < 12; ++cc) o[obase + cc] = acc[cc];
    }
}

extern "C" void kernel_launch(void* const* d_in, const int* in_sizes, int n_in,
                              void* d_out, int out_size, void* d_ws, size_t ws_size,
                              hipStream_t stream)
{
    (void)out_size; (void)ws_size;
    float* ws = (float*)d_ws;
    int* flag = (int*)ws;

    // converted weight region (inputs 1..11), starts at 64, ends < 131072
    int off[12]; int tot = 64;
    off[0] = 0;
    for (int i = 1; i < 12; ++i) {
        off[i] = tot;
        int n = (i < n_in) ? in_sizes[i] : 0;
        tot += (n + 63) & ~63;
    }
    float* winf = ws + off[1];
    float* cwf  = ws + off[2];
    float* cbf  = ws + off[3];
    float* xpwf = ws + off[4];
    float* dtwf = ws + off[5];
    float* dtbf = ws + off[6];
    float* alogf= ws + off[7];
    float* dsf  = ws + off[8];
    float* nwf  = ws + off[9];
    float* nbf  = ws + off[10];
    float* wof  = ws + off[11];

    const size_t BASE = 131072;
    __half* dtH = (__half*)(ws + BASE);            // 6291456 h  (B,K,Di,L)
    float*  xc  = ws + BASE + 3145728;             // 1572864 f  (B,Di,L)
    float*  uT  = ws + BASE + 4849664 - 131072 + 131072; // keep arithmetic simple below
    uT          = ws + BASE + 3145728 + 1572864;   // 1572864 f
    float*  BsT = ws + BASE + 6291456;             // 524288 f   (B,K,N,L)
    float*  CsT = ws + BASE + 6815744;             // 524288 f
    float*  P   = ws + BASE + 7340032;             // 786432 f   (chains,NC,16); alias ysT after k7
    float*  S   = ws + BASE + 8126464;             // 786432 f   ; alias gH after k6
    __half* zsH = (__half*)(ws + BASE + 8912896);  // 1572864 h  (B,L,Di)
    float*  xi  = ws + BASE + 9699328;             // 1572864 f  (B,L,Di); aliased under ys
    __half* ysH = (__half*)(ws + BASE + 9699328);  // 6291456 h  (K,B,Di,L)
    __half* ysT = (__half*)P;                      // 1572864 h  (B,Di,L)
    __half* gH  = (__half*)S;                      // 1572864 h  (B,L,Di)
    // end = BASE + 12845056 = 12,976,128 floats = 51.9 MB

    Cv cv;
    for (int i = 0; i < 11; ++i) {
        int t = i + 1;
        cv.src[i] = (t < n_in) ? d_in[t] : d_in[0];
        cv.off[i] = off[t];
        cv.n[i]   = (t < n_in) ? in_sizes[t] : 0;
    }

    k0_detect  <<<dim3(1),    dim3(256), 0, stream>>>((const unsigned short*)d_in[0], flag);
    k0b_convert<<<dim3(144, 11), dim3(256), 0, stream>>>(cv, flag, ws);
    k1_inproj  <<<dim3(1024), dim3(256), 0, stream>>>(d_in[0], flag, winf, xi, zsH);
    k2_conv    <<<dim3(256),  dim3(192), 0, stream>>>(xi, cwf, cbf, xc);
    k3_proj    <<<dim3(512),  dim3(256), 0, stream>>>(xc, xpwf, dtwf, dtbf, dtH, BsT, CsT);
    k4_ut      <<<dim3(384),  dim3(256), 0, stream>>>(xc, uT);
    kscan<0,0> <<<dim3(1536), dim3(256), 0, stream>>>(dtH, xc, uT, BsT, CsT, alogf, dsf, P, S, ysH, 0);
    kscan<1,0> <<<dim3(1536), dim3(256), 0, stream>>>(dtH, xc, uT, BsT, CsT, alogf, dsf, P, S, ysH, 2);
    k6_pass2   <<<dim3(96),   dim3(256), 0, stream>>>(P, S);
    kscan<0,1> <<<dim3(1536), dim3(256), 0, stream>>>(dtH, xc, uT, BsT, CsT, alogf, dsf, P, S, ysH, 0);
    kscan<1,1> <<<dim3(1536), dim3(256), 0, stream>>>(dtH, xc, uT, BsT, CsT, alogf, dsf, P, S, ysH, 2);
    k8t        <<<dim3(384),  dim3(256), 0, stream>>>(ysH, ysT);
    k8_norm    <<<dim3(256),  dim3(256), 0, stream>>>(ysH, ysT, zsH, nwf, nbf, gH);
    k10_outproj<<<dim3(256),  dim3(256), 0, stream>>>(gH, wof, flag, d_out);
}

// Round 4
// 306.572 us; speedup vs baseline: 1.3419x; 1.1923x over previous
//
#include <hip/hip_runtime.h>
#include <hip/hip_fp16.h>
#include <math.h>

// SS2D fused block. B=2, H=W=64, L=4096, C=96, Di=192, K=4, N=16, R=6.
// Input dtype (bf16 vs f32) detected at runtime; internal compute f32 (dt/z/ys f16).
// Workspace: ~52 MB.

static constexpr int Bsz = 2;
static constexpr int Lc  = 4096;
static constexpr int Cc  = 96;
static constexpr int Dd  = 192;
static constexpr int Kk  = 4;
static constexpr int NC  = 32;     // chunks of 128 steps

__device__ __forceinline__ float bu(unsigned short v) {
    return __uint_as_float((unsigned int)v << 16);
}
__device__ __forceinline__ unsigned short f2b(float f) {
    unsigned int u = __float_as_uint(f);
    return (unsigned short)((u + 0x7fffu + ((u >> 16) & 1u)) >> 16);
}

// ---------------- K0: dtype detector (bf16 vs f32) ----------------
__global__ __launch_bounds__(256) void k0_detect(const unsigned short* __restrict__ x,
                                                 int* __restrict__ flag)
{
    __shared__ int s[256];
    int cnt = 0;
    for (int i = threadIdx.x; i < 4096; i += 256) {
        int e = (x[i] >> 7) & 0xFF;
        cnt += (e >= 118 && e <= 131) ? 1 : 0;
    }
    s[threadIdx.x] = cnt;
    __syncthreads();
    for (int st = 128; st > 0; st >>= 1) {
        if (threadIdx.x < st) s[threadIdx.x] += s[threadIdx.x + st];
        __syncthreads();
    }
    if (threadIdx.x == 0) flag[0] = (s[0] >= 3072) ? 1 : 0;
}

// ---------------- K0b: convert weight inputs (1..11) to canonical f32 ----------------
struct Cv {
    const void* src[11];
    int off[11];
    int n[11];
};
__global__ __launch_bounds__(256) void k0b_convert(Cv cv, const int* __restrict__ flag,
                                                   float* __restrict__ dstbase)
{
    int bf = flag[0];
    int t = blockIdx.y;
    int i = blockIdx.x * 256 + threadIdx.x;
    if (i >= cv.n[t]) return;
    float v;
    if (bf) v = bu(((const unsigned short*)cv.src[t])[i]);
    else    v = ((const float*)cv.src[t])[i];
    dstbase[cv.off[t] + i] = v;
}

// ---------------- K1: in_proj GEMM (8192x384x96), split xi / silu(z) ----------------
__global__ __launch_bounds__(256) void k1_inproj(const void* __restrict__ xraw,
                                                 const int* __restrict__ flag,
                                                 const float* __restrict__ wf,
                                                 float* __restrict__ xi, __half* __restrict__ zs)
{
    __shared__ float xT[32 * 97];
    __shared__ float wT[96 * 97];
    const int bf = flag[0];
    int tile = blockIdx.x >> 2, jq = blockIdx.x & 3;
    int b = tile >> 7;
    int l0 = (tile & 127) << 5;
    int j0 = jq * 96;
    for (int e = threadIdx.x; e < 32 * 96; e += 256) {
        int i = e / 96, c = e % 96;
        size_t idx = (size_t)(b * Lc + l0 + i) * Cc + c;
        xT[i * 97 + c] = bf ? bu(((const unsigned short*)xraw)[idx])
                            : ((const float*)xraw)[idx];
    }
    for (int e = threadIdx.x; e < 96 * 96; e += 256) {
        int j = e / 96, c = e % 96;
        wT[j * 97 + c] = wf[(size_t)(j0 + j) * Cc + c];
    }
    __syncthreads();
    int jj = threadIdx.x & 31, ll = threadIdx.x >> 5;
    float acc[4][3];
#pragma unroll
    for (int i = 0; i < 4; i++)
#pragma unroll
        for (int m = 0; m < 3; m++) acc[i][m] = 0.f;
    for (int c = 0; c < 96; ++c) {
        float xv[4], wv[3];
#pragma unroll
        for (int i = 0; i < 4; i++) xv[i] = xT[(ll * 4 + i) * 97 + c];
#pragma unroll
        for (int m = 0; m < 3; m++) wv[m] = wT[(jj + 32 * m) * 97 + c];
#pragma unroll
        for (int i = 0; i < 4; i++)
#pragma unroll
            for (int m = 0; m < 3; m++) acc[i][m] += xv[i] * wv[m];
    }
#pragma unroll
    for (int i = 0; i < 4; i++) {
        int l = l0 + ll * 4 + i;
#pragma unroll
        for (int m = 0; m < 3; m++) {
            int j = j0 + jj + 32 * m;
            float v = acc[i][m];
            if (j < Dd) xi[(size_t)(b * Lc + l) * Dd + j] = v;
            else        zs[(size_t)(b * Lc + l) * Dd + (j - Dd)] = __float2half(v / (1.f + __expf(-v)));
        }
    }
}

// ---------------- K2a: transpose xi (B,L,Di) -> xiT (B,Di,L) ----------------
__global__ __launch_bounds__(256) void k2a_transpose(const float* __restrict__ xi,
                                                     float* __restrict__ xiT)
{
    __shared__ float t[64 * 65];
    int bid = blockIdx.x;
    int lq = bid & 63, dq = (bid >> 6) % 3, b = bid / 192;
    int l0 = lq * 64, d0 = dq * 64;
    for (int e = threadIdx.x; e < 4096; e += 256) {
        int i = e >> 6, j = e & 63;
        t[i * 65 + j] = xi[(size_t)(b * Lc + l0 + i) * Dd + d0 + j];
    }
    __syncthreads();
    for (int e = threadIdx.x; e < 4096; e += 256) {
        int j = e >> 6, i = e & 63;
        xiT[(size_t)(b * Dd + d0 + j) * Lc + l0 + i] = t[i * 65 + j];
    }
}

// -------- K2b: depthwise 3x3 conv + bias + SiLU (channel-first), writes xc and uT --------
__global__ __launch_bounds__(256) void k2b_conv(const float* __restrict__ xiT,
                                                const float* __restrict__ cwf,
                                                const float* __restrict__ cbf,
                                                float* __restrict__ xc,
                                                float* __restrict__ uT)
{
    __shared__ float inl[34 * 66];   // rows h0-1..h0+32, cols zero-padded
    __shared__ float outl[32 * 65];
    int bid = blockIdx.x;
    int half = bid & 1;
    int d = (bid >> 1) % Dd;
    int b = bid / (2 * Dd);
    int h0 = half * 32;
    const float* src = xiT + (size_t)(b * Dd + d) * Lc;
    // zero-pad columns
    for (int r = threadIdx.x; r < 34; r += 256) {
        inl[r * 66 + 0] = 0.f;
        inl[r * 66 + 65] = 0.f;
    }
    // load 34 rows x 64 cols (h boundary rows -> 0)
    for (int e = threadIdx.x; e < 34 * 64; e += 256) {
        int row = e >> 6, w = e & 63;
        int h = h0 - 1 + row;
        inl[row * 66 + 1 + w] = (h >= 0 && h < 64) ? src[h * 64 + w] : 0.f;
    }
    __syncthreads();
    float wgt[9];
#pragma unroll
    for (int t = 0; t < 9; t++) wgt[t] = cwf[d * 9 + t];
    float bias = cbf[d];
    int hs = threadIdx.x >> 6, w = threadIdx.x & 63;
    float* dstrow = xc + (size_t)(b * Dd + d) * Lc;
#pragma unroll
    for (int it = 0; it < 8; ++it) {
        int hh = it * 4 + hs;
        float acc = bias;
#pragma unroll
        for (int dy = 0; dy < 3; ++dy) {
            const float* rp = &inl[(hh + dy) * 66 + w];
#pragma unroll
            for (int dx = 0; dx < 3; ++dx)
                acc += rp[dx] * wgt[dy * 3 + dx];
        }
        float s = acc / (1.f + __expf(-acc));
        dstrow[(h0 + hh) * 64 + w] = s;
        outl[hh * 65 + w] = s;
    }
    __syncthreads();
    float* udst = uT + (size_t)(b * Dd + d) * Lc;
    for (int e = threadIdx.x; e < 2048; e += 256) {
        int w2 = e >> 5, hh2 = e & 31;
        udst[w2 * 64 + h0 + hh2] = outl[hh2 * 65 + w2];
    }
}

// -------- K3: per-direction projection (38 outs) + dt-proj + softplus --------
__global__ __launch_bounds__(256) void k3_proj(const float* __restrict__ xc,
                                               const float* __restrict__ xpwf,
                                               const float* __restrict__ dtwf,
                                               const float* __restrict__ dtbf,
                                               __half* __restrict__ dtH,
                                               float* __restrict__ BsT, float* __restrict__ CsT)
{
    __shared__ float Wl[192 * 40];
    __shared__ float dtWl[192 * 8];
    __shared__ float biasl[192];
    __shared__ float rawq[4][64 * 41];
    int bid = blockIdx.x;
    int pt = bid & 63, k = (bid >> 6) & 3, b = bid >> 8;
    bool colm = (k & 1);
    int s0 = pt * 64;
    for (int e = threadIdx.x; e < 38 * 192; e += 256) {
        int cp = e / 192, d = e % 192;
        Wl[d * 40 + cp] = xpwf[(size_t)(k * 38 + cp) * 192 + d];
    }
    for (int e = threadIdx.x; e < 2 * 192; e += 256) {
        Wl[(e >> 1) * 40 + 38 + (e & 1)] = 0.f;
    }
    for (int e = threadIdx.x; e < 192 * 6; e += 256) {
        int d = e / 6, r = e % 6;
        dtWl[d * 8 + r] = dtwf[(size_t)(k * 192 + d) * 6 + r];
    }
    for (int e = threadIdx.x; e < 192; e += 256) biasl[e] = dtbf[k * 192 + e];
    __syncthreads();
    int pi = threadIdx.x & 63, q = threadIdx.x >> 6;
    int pos = colm ? (pi * 64 + pt) : (pt * 64 + pi);
    float acc[40];
#pragma unroll
    for (int i = 0; i < 40; i++) acc[i] = 0.f;
    const float* xrow = xc + (size_t)b * Dd * Lc + pos;
    for (int dd = 0; dd < 48; ++dd) {
        int d = q * 48 + dd;
        float xv = xrow[(size_t)d * Lc];
#pragma unroll
        for (int c4 = 0; c4 < 10; ++c4) {
            float4 w4 = *reinterpret_cast<const float4*>(&Wl[d * 40 + c4 * 4]);
            acc[c4 * 4 + 0] += w4.x * xv; acc[c4 * 4 + 1] += w4.y * xv;
            acc[c4 * 4 + 2] += w4.z * xv; acc[c4 * 4 + 3] += w4.w * xv;
        }
    }
    float* myraw = &rawq[q][pi * 41];
#pragma unroll
    for (int i = 0; i < 40; i++) myraw[i] = acc[i];
    __syncthreads();
    for (int e = threadIdx.x; e < 64 * 40; e += 256) {
        int p = e / 40, cp = e % 40;
        rawq[0][p * 41 + cp] = rawq[0][p * 41 + cp] + rawq[1][p * 41 + cp]
                             + rawq[2][p * 41 + cp] + rawq[3][p * 41 + cp];
    }
    __syncthreads();
    // B/C transposed: [ (b,k) ][ n ][ t ]  (f32)
    for (int e = threadIdx.x; e < 64 * 16; e += 256) {
        int n = e >> 6, p = e & 63;
        size_t base = ((size_t)((b * Kk + k) * 16 + n)) * Lc + s0 + p;
        BsT[base] = rawq[0][p * 41 + 6 + n];
        CsT[base] = rawq[0][p * 41 + 22 + n];
    }
    for (int dd = 0; dd < 48; ++dd) {
        int d = q * 48 + dd;
        float s = biasl[d];
#pragma unroll
        for (int r = 0; r < 6; r++) s += rawq[0][pi * 41 + r] * dtWl[d * 8 + r];
        float sp = fmaxf(s, 0.f) + log1pf(__expf(-fabsf(s)));
        dtH[((size_t)(b * Kk + k) * Dd + d) * Lc + s0 + pi] = __float2half(sp);
    }
}

// ---------------- KSCAN: chunked selective scan (pass1 / pass3) ----------------
template<int REV, int PASS3>
__global__ __launch_bounds__(256) void kscan(const __half* __restrict__ dtH,
                                             const float* __restrict__ xc,
                                             const float* __restrict__ uT,
                                             const float* __restrict__ BsT,
                                             const float* __restrict__ CsT,
                                             const float* __restrict__ alogf,
                                             const float* __restrict__ dsf,
                                             float* __restrict__ P,       // pass1: out; pass3: Hin
                                             float* __restrict__ S,       // pass1 out
                                             __half* __restrict__ ysH,
                                             int kbase)
{
    int c  = blockIdx.x & 31;
    int t1 = blockIdx.x >> 5;
    int dg = t1 % 12;
    int kk = kbase + ((t1 / 12) & 1);
    int b  = t1 / 24;
    int n  = threadIdx.x & 15, dl = threadIdx.x >> 4;
    int d  = dg * 16 + dl;

    const __half* dtp = dtH + ((size_t)((b * Kk + kk) * Dd + d)) * Lc;
    const float*  up  = (kk & 1) ? uT + (size_t)(b * Dd + d) * Lc
                                 : xc + (size_t)(b * Dd + d) * Lc;
    const float*  Bn  = BsT + ((size_t)((b * Kk + kk) * 16 + n)) * Lc;
    const float*  Cn  = CsT + ((size_t)((b * Kk + kk) * 16 + n)) * Lc;
    float An = -__expf(alogf[(kk * Dd + d) * 16 + n]);
    size_t pidx = (((size_t)(b * Kk + kk) * Dd + d) * NC + c) * 16 + n;

    float h, sdt = 0.f, Dsv = 0.f, ystash = 0.f;
    __half* yrow = nullptr;
    if (PASS3) {
        h = P[pidx];                       // carry-in
        Dsv = dsf[kk * Dd + d];
        yrow = ysH + ((size_t)(kk * Bsz + b) * Dd + d) * Lc;
    } else h = 0.f;

    int t0 = c * 128;
    for (int s = 0; s < 8; ++s) {
        int tg = t0 + s * 16;
        int mb = REV ? (Lc - 16 - tg) : tg;     // aligned 16-element base
        float4 uq[4], bq[4], cq[4];
        {
            const float4* p4 = reinterpret_cast<const float4*>(up + mb);
            uq[0] = p4[0]; uq[1] = p4[1]; uq[2] = p4[2]; uq[3] = p4[3];
        }
        {
            const float4* p4 = reinterpret_cast<const float4*>(Bn + mb);
            bq[0] = p4[0]; bq[1] = p4[1]; bq[2] = p4[2]; bq[3] = p4[3];
        }
        if (PASS3) {
            const float4* p4 = reinterpret_cast<const float4*>(Cn + mb);
            cq[0] = p4[0]; cq[1] = p4[1]; cq[2] = p4[2]; cq[3] = p4[3];
        }
        __half2 dh[8];
        {
            const __half2* p2 = reinterpret_cast<const __half2*>(dtp + mb);
#pragma unroll
            for (int i = 0; i < 8; ++i) dh[i] = p2[i];
        }
#pragma unroll
        for (int j = 0; j < 16; ++j) {
            const int m = REV ? (15 - j) : j;
            float dtv = (m & 1) ? __high2float(dh[m >> 1]) : __low2float(dh[m >> 1]);
            float uv  = reinterpret_cast<const float*>(uq)[m];
            float bv  = reinterpret_cast<const float*>(bq)[m];
            float a   = __expf(dtv * An);
            if (!PASS3) sdt += dtv;
            h = a * h + (dtv * uv) * bv;
            if (PASS3) {
                float cv = reinterpret_cast<const float*>(cq)[m];
                float yv = h * cv;
                yv += __shfl_xor(yv, 1, 16);
                yv += __shfl_xor(yv, 2, 16);
                yv += __shfl_xor(yv, 4, 16);
                yv += __shfl_xor(yv, 8, 16);
                if (j == n) ystash = yv + uv * Dsv;
            }
        }
        if (PASS3) {
            int tb = tg + n;
            int aw = REV ? (Lc - 1 - tb) : tb;
            yrow[aw] = __float2half(ystash);    // 16-lane coalesced
        }
    }
    if (!PASS3) {
        P[pidx] = __expf(An * sdt);             // prod of a over chunk
        S[pidx] = h;
    }
}

// ---------------- K6: chunk-level scan; carry-in written in place over P ----------------
__global__ __launch_bounds__(256) void k6_pass2(float* __restrict__ P, const float* __restrict__ S)
{
    int g = blockIdx.x * 256 + threadIdx.x;   // 24576
    int n = g & 15;
    int chain = g >> 4;
    size_t base = (size_t)chain * NC * 16 + n;
    float h = 0.f;
    for (int c = 0; c < NC; ++c) {
        size_t id = base + (size_t)c * 16;
        float p = P[id], s = S[id];
        P[id] = h;
        h = p * h + s;
    }
}

// ---------------- K8t: ysT = transpose(ys1 + ys3) per (b,d) ----------------
__global__ __launch_bounds__(256) void k8t(const __half* __restrict__ ysH,
                                           __half* __restrict__ ysT)
{
    __shared__ float t[64 * 65];
    int bid = blockIdx.x;
    int d = bid % Dd, b = bid / Dd;
    const __half* y1 = ysH + ((size_t)(1 * Bsz + b) * Dd + d) * Lc;
    const __half* y3 = ysH + ((size_t)(3 * Bsz + b) * Dd + d) * Lc;
    __half* dst = ysT + ((size_t)b * Dd + d) * Lc;
    for (int e = threadIdx.x; e < 4096; e += 256)
        t[(e >> 6) * 65 + (e & 63)] = __half2float(y1[e]) + __half2float(y3[e]);
    __syncthreads();
    for (int e = threadIdx.x; e < 4096; e += 256)
        dst[e] = __float2half(t[(e & 63) * 65 + (e >> 6)]);
}

// ---------------- K8: merge + LayerNorm + SiLU(z) gate -> gH ----------------
__global__ __launch_bounds__(256) void k8_norm(const __half* __restrict__ ysH,
                                               const __half* __restrict__ ysT,
                                               const __half* __restrict__ zsH,
                                               const float* __restrict__ nwf,
                                               const float* __restrict__ nbf,
                                               __half* __restrict__ gH)
{
    __shared__ float yt[192 * 33];
    __shared__ float ps1[8 * 32], ps2[8 * 32];
    __shared__ float mu[32], rs[32];
    int bid = blockIdx.x;
    int pt = bid & 127, b = bid >> 7;
    int p0 = pt * 32;
    for (int e = threadIdx.x; e < 192 * 32; e += 256) {
        int d = e >> 5, p = e & 31;
        size_t r0 = ((size_t)(0 * Bsz + b) * Dd + d) * Lc + p0 + p;
        size_t r2 = ((size_t)(2 * Bsz + b) * Dd + d) * Lc + p0 + p;
        size_t rt = ((size_t)b * Dd + d) * Lc + p0 + p;
        yt[d * 33 + p] = __half2float(ysH[r0]) + __half2float(ysH[r2]) + __half2float(ysT[rt]);
    }
    __syncthreads();
    {
        int p = threadIdx.x & 31, q = threadIdx.x >> 5;
        float s1 = 0.f, s2 = 0.f;
        for (int dd = 0; dd < 24; ++dd) {
            float v = yt[(q * 24 + dd) * 33 + p];
            s1 += v; s2 += v * v;
        }
        ps1[q * 32 + p] = s1; ps2[q * 32 + p] = s2;
    }
    __syncthreads();
    if (threadIdx.x < 32) {
        int p = threadIdx.x;
        float s1 = 0.f, s2 = 0.f;
        for (int q = 0; q < 8; ++q) { s1 += ps1[q * 32 + p]; s2 += ps2[q * 32 + p]; }
        float m = s1 * (1.f / 192.f);
        float var = s2 * (1.f / 192.f) - m * m;
        mu[p] = m; rs[p] = rsqrtf(var + 1e-5f);
    }
    __syncthreads();
    for (int i = threadIdx.x; i < 32 * 192; i += 256) {
        int p = i / 192, d = i - p * 192;
        float v = (yt[d * 33 + p] - mu[p]) * rs[p] * nwf[d] + nbf[d];
        size_t addr = ((size_t)b * Lc + p0 + p) * Dd + d;
        float zv = __half2float(zsH[addr]);
        gH[addr] = __float2half(v * zv);
    }
}

// ---------------- K10: out_proj GEMM (8192 x 96 x 192) ----------------
__global__ __launch_bounds__(256) void k10_outproj(const __half* __restrict__ gH,
                                                   const float* __restrict__ wof,
                                                   const int* __restrict__ flag,
                                                   void* __restrict__ outv)
{
    __shared__ float wT[192 * 100];   // [d][c], padded
    const int bf = flag[0];
    for (int e = threadIdx.x; e < 96 * 192; e += 256) {
        int cI = e / 192, dI = e - cI * 192;
        wT[dI * 100 + cI] = wof[e];
    }
    __syncthreads();
    int r0 = blockIdx.x * 32;
    int r = threadIdx.x >> 3, cg = threadIdx.x & 7;
    const __half* grow = gH + (size_t)(r0 + r) * Dd;
    float acc[12];
#pragma unroll
    for (int i = 0; i < 12; ++i) acc[i] = 0.f;
    for (int d0 = 0; d0 < 192; d0 += 8) {
        __half2 g2[4];
        *reinterpret_cast<uint4*>(g2) = *reinterpret_cast<const uint4*>(grow + d0);
#pragma unroll
        for (int j = 0; j < 8; ++j) {
            float gf = (j & 1) ? __high2float(g2[j >> 1]) : __low2float(g2[j >> 1]);
            const float* wrow = &wT[(d0 + j) * 100 + cg * 12];
            float4 w0 = *reinterpret_cast<const float4*>(wrow);
            float4 w1 = *reinterpret_cast<const float4*>(wrow + 4);
            float4 w2 = *reinterpret_cast<const float4*>(wrow + 8);
            acc[0] += gf * w0.x; acc[1] += gf * w0.y; acc[2]  += gf * w0.z; acc[3]  += gf * w0.w;
            acc[4] += gf * w1.x; acc[5] += gf * w1.y; acc[6]  += gf * w1.z; acc[7]  += gf * w1.w;
            acc[8] += gf * w2.x; acc[9] += gf * w2.y; acc[10] += gf * w2.z; acc[11] += gf * w2.w;
        }
    }
    size_t obase = (size_t)(r0 + r) * Cc + cg * 12;
    if (bf) {
        unsigned short* o = (unsigned short*)outv;
#pragma unroll
        for (int cc = 0; cc < 12; ++cc) o[obase + cc] = f2b(acc[cc]);
    } else {
        float* o = (float*)outv;
#pragma unroll
        for (int cc = 0; cc < 12; ++cc) o[obase + cc] = acc[cc];
    }
}

extern "C" void kernel_launch(void* const* d_in, const int* in_sizes, int n_in,
                              void* d_out, int out_size, void* d_ws, size_t ws_size,
                              hipStream_t stream)
{
    (void)out_size; (void)ws_size;
    float* ws = (float*)d_ws;
    int* flag = (int*)ws;

    // converted weight region (inputs 1..11), starts at 64, ends < 131072
    int off[12]; int tot = 64;
    off[0] = 0;
    for (int i = 1; i < 12; ++i) {
        off[i] = tot;
        int n = (i < n_in) ? in_sizes[i] : 0;
        tot += (n + 63) & ~63;
    }
    float* winf = ws + off[1];
    float* cwf  = ws + off[2];
    float* cbf  = ws + off[3];
    float* xpwf = ws + off[4];
    float* dtwf = ws + off[5];
    float* dtbf = ws + off[6];
    float* alogf= ws + off[7];
    float* dsf  = ws + off[8];
    float* nwf  = ws + off[9];
    float* nbf  = ws + off[10];
    float* wof  = ws + off[11];

    const size_t BASE = 131072;
    __half* dtH = (__half*)(ws + BASE);            // 6291456 h  (B,K,Di,L)
    float*  xc  = ws + BASE + 3145728;             // 1572864 f  (B,Di,L)
    float*  uT  = ws + BASE + 4718592;             // 1572864 f  (B,Di,L) col-major
    float*  BsT = ws + BASE + 6291456;             // 524288 f   (B,K,N,L)
    float*  CsT = ws + BASE + 6815744;             // 524288 f
    float*  P   = ws + BASE + 7340032;             // 786432 f   ; alias ysT after pass3
    float*  S   = ws + BASE + 8126464;             // 786432 f   ; alias gH after k6
    __half* zsH = (__half*)(ws + BASE + 8912896);  // 1572864 h  (B,L,Di)
    float*  xi  = ws + BASE + 9699328;             // 1572864 f  (B,L,Di); dead after k2a
    float*  xiT = ws + BASE + 9699328 + 1572864;   // 1572864 f  (B,Di,L); dead after k2b
    __half* ysH = (__half*)(ws + BASE + 9699328);  // 6291456 h  (K,B,Di,L) — overlays xi/xiT
    __half* ysT = (__half*)P;                      // 1572864 h  (B,Di,L)
    __half* gH  = (__half*)S;                      // 1572864 h  (B,L,Di)
    // end = BASE + 12845056 floats = 51.9 MB

    Cv cv;
    for (int i = 0; i < 11; ++i) {
        int t = i + 1;
        cv.src[i] = (t < n_in) ? d_in[t] : d_in[0];
        cv.off[i] = off[t];
        cv.n[i]   = (t < n_in) ? in_sizes[t] : 0;
    }

    k0_detect   <<<dim3(1),    dim3(256), 0, stream>>>((const unsigned short*)d_in[0], flag);
    k0b_convert <<<dim3(144, 11), dim3(256), 0, stream>>>(cv, flag, ws);
    k1_inproj   <<<dim3(1024), dim3(256), 0, stream>>>(d_in[0], flag, winf, xi, zsH);
    k2a_transpose<<<dim3(384), dim3(256), 0, stream>>>(xi, xiT);
    k2b_conv    <<<dim3(768),  dim3(256), 0, stream>>>(xiT, cwf, cbf, xc, uT);
    k3_proj     <<<dim3(512),  dim3(256), 0, stream>>>(xc, xpwf, dtwf, dtbf, dtH, BsT, CsT);
    kscan<0,0>  <<<dim3(1536), dim3(256), 0, stream>>>(dtH, xc, uT, BsT, CsT, alogf, dsf, P, S, ysH, 0);
    kscan<1,0>  <<<dim3(1536), dim3(256), 0, stream>>>(dtH, xc, uT, BsT, CsT, alogf, dsf, P, S, ysH, 2);
    k6_pass2    <<<dim3(96),   dim3(256), 0, stream>>>(P, S);
    kscan<0,1>  <<<dim3(1536), dim3(256), 0, stream>>>(dtH, xc, uT, BsT, CsT, alogf, dsf, P, S, ysH, 0);
    kscan<1,1>  <<<dim3(1536), dim3(256), 0, stream>>>(dtH, xc, uT, BsT, CsT, alogf, dsf, P, S, ysH, 2);
    k8t         <<<dim3(384),  dim3(256), 0, stream>>>(ysH, ysT);
    k8_norm     <<<dim3(256),  dim3(256), 0, stream>>>(ysH, ysT, zsH, nwf, nbf, gH);
    k10_outproj <<<dim3(256),  dim3(256), 0, stream>>>(gH, wof, flag, d_out);
}